// Round 6
// baseline (1465.449 us; speedup 1.0000x reference)
//
#include <hip/hip_runtime.h>
#include <hip/hip_bf16.h>
#include <math.h>

#define BATCH 8
#define CH 64
#define HH 256
#define WW 256
#define HID 512
#define NE 4

typedef short v8s __attribute__((ext_vector_type(8)));
typedef float v4f __attribute__((ext_vector_type(4)));
typedef float v16f __attribute__((ext_vector_type(16)));

static __device__ __forceinline__ unsigned short f2bf(float v) {
    __hip_bfloat16 h = __float2bfloat16(v);
    return *(unsigned short*)&h;
}

// ---------------- K1: per-(b,c) spatial mean -> g[8*64] ----------------
__global__ __launch_bounds__(256) void mean_kernel(const float* __restrict__ x,
                                                   float* __restrict__ g) {
    int bc = blockIdx.x;
    const float* p = x + (size_t)bc * (HH * WW);
    float s = 0.f;
    for (int i = threadIdx.x; i < HH * WW; i += 256) s += p[i];
    __shared__ float red[256];
    red[threadIdx.x] = s;
    __syncthreads();
    for (int off = 128; off > 0; off >>= 1) {
        if (threadIdx.x < off) red[threadIdx.x] += red[threadIdx.x + off];
        __syncthreads();
    }
    if (threadIdx.x == 0) g[bc] = red[0] * (1.0f / (HH * WW));
}

// ---------------- K2: gating MLP + softmax + top2 + coef + loss --------
__global__ __launch_bounds__(512) void gate_kernel(const float* __restrict__ g,
                                                   const float* __restrict__ gw1,
                                                   const float* __restrict__ gb1,
                                                   const float* __restrict__ gw2,
                                                   const float* __restrict__ gb2,
                                                   float* __restrict__ coef_out,
                                                   float* __restrict__ loss_out) {
    __shared__ float h[BATCH][HID];
    __shared__ float logits[BATCH][NE];
    int t = threadIdx.x;
    for (int b = 0; b < BATCH; b++) {
        float acc = gb1[t];
        for (int c = 0; c < CH; c++) acc = fmaf(g[b * CH + c], gw1[t * CH + c], acc);
        h[b][t] = fmaxf(acc, 0.f);
    }
    __syncthreads();
    if (t < BATCH * NE) {
        int b = t / NE, e = t % NE;
        float acc = gb2[e];
        for (int j = 0; j < HID; j++) acc = fmaf(h[b][j], gw2[e * HID + j], acc);
        logits[b][e] = acc;
    }
    __syncthreads();
    if (t == 0) {
        float sm[BATCH][NE];
        for (int b = 0; b < BATCH; b++) {
            float m = logits[b][0];
            for (int e = 1; e < NE; e++) m = fmaxf(m, logits[b][e]);
            float s = 0.f;
            for (int e = 0; e < NE; e++) { sm[b][e] = expf(logits[b][e] - m); s += sm[b][e]; }
            for (int e = 0; e < NE; e++) sm[b][e] /= s;
        }
        float mean = 0.f;
        for (int b = 0; b < BATCH; b++)
            for (int e = 0; e < NE; e++) mean += sm[b][e];
        mean *= 1.0f / (BATCH * NE);
        float var = 0.f;
        for (int b = 0; b < BATCH; b++)
            for (int e = 0; e < NE; e++) {
                float d = sm[b][e] - mean;
                var += d * d;
            }
        var *= 1.0f / (BATCH * NE - 1);
        *loss_out = sqrtf(var) / (mean + 1e-10f) * 0.1f;
        float coef[NE] = {0.f, 0.f, 0.f, 0.f};
        for (int b = 0; b < BATCH; b++) {
            int i0 = 0;
            for (int e = 1; e < NE; e++)
                if (sm[b][e] > sm[b][i0]) i0 = e;
            int i1 = -1;
            for (int e = 0; e < NE; e++) {
                if (e == i0) continue;
                if (i1 < 0 || sm[b][e] > sm[b][i1]) i1 = e;
            }
            float v0 = sm[b][i0], v1 = sm[b][i1];
            float be = expf(v1 - v0);
            float a0 = 1.f / (1.f + be);
            float a1 = be / (1.f + be);
            coef[i0] += a0;
            coef[i1] += a1;
        }
        for (int e = 0; e < NE; e++) coef_out[e] = coef[e];
    }
}

// ---------------- K3a: weights OIHW fp32 -> wT bf16, COALESCED layout --
// Per-tap layout (4096 shorts = 8192 B per tap, tap-major):
//   [nt(2)][kc(4)][lane(64)][8 shorts]   lane = kh*32 + n
// holds w[co = nt*32+n][ci = kc*16 + kh*8 + j], j=0..7. A wave's load for
// chunk (nt,kc) is base + lane*16: 64 lanes x 16 B CONTIGUOUS. kc slabs
// are contiguous, so a ci-half (kc pair) is a +h*2048 B offset.
__global__ __launch_bounds__(256) void wtrans_kernel(const float* __restrict__ ew1,
                                                     const float* __restrict__ ew3,
                                                     const float* __restrict__ ew7,
                                                     const float* __restrict__ ew11,
                                                     unsigned short* __restrict__ wT) {
    int gid = blockIdx.x * 256 + threadIdx.x;  // < 180*512 = 92160
    int tapg = gid >> 9;
    int rem = gid & 511;
    int co = rem >> 3, kg = rem & 7;
    const float* src;
    int k, tap, dstbase;
    if (tapg < 1) { src = ew1; k = 1; tap = tapg; dstbase = 0; }
    else if (tapg < 10) { src = ew3; k = 3; tap = tapg - 1; dstbase = 1 * 4096; }
    else if (tapg < 59) { src = ew7; k = 7; tap = tapg - 10; dstbase = 10 * 4096; }
    else { src = ew11; k = 11; tap = tapg - 59; dstbase = 59 * 4096; }
    int ky = tap / k, kx = tap - ky * k;
    unsigned short o[8];
#pragma unroll
    for (int j = 0; j < 8; j++) {
        int ci = kg * 8 + j;
        o[j] = f2bf(src[((co * 64 + ci) * k + ky) * k + kx]);
    }
    int nt = co >> 5, nn = co & 31, kc = kg >> 1, khp = kg & 1;
    *(v8s*)(wT + (size_t)dstbase + (size_t)tap * 4096 +
            ((nt * 4 + kc) * 64 + khp * 32 + nn) * 8) = *(v8s*)o;
}

// ---------------- K3b: x NCHW fp32 -> xT[b][y][x][ci] bf16 -------------
#define XP 258
__global__ __launch_bounds__(256) void xtrans_kernel(const float* __restrict__ x,
                                                     unsigned short* __restrict__ xT) {
    __shared__ unsigned short t[64 * XP];
    int blk = blockIdx.x;  // b*256 + y
    int b = blk >> 8, y = blk & 255;
    int tid = threadIdx.x;
    for (int ci = 0; ci < 64; ci++) {
        float v = x[((size_t)(b * 64 + ci)) * 65536 + (size_t)y * 256 + tid];
        t[ci * XP + tid] = f2bf(v);
    }
    __syncthreads();
    unsigned short* dst = xT + (size_t)blk * 256 * 64;
    for (int c = tid; c < 2048; c += 256) {
        int xx = c >> 3, kg = c & 7;
        unsigned short o[8];
#pragma unroll
        for (int j = 0; j < 8; j++) o[j] = t[(kg * 8 + j) * XP + xx];
        *(v8s*)(dst + (size_t)xx * 64 + kg * 8) = *(v8s*)o;
    }
}

// ---------------- K4: 32x32x16 MFMA expert-sequential fused conv -------
// R6 CHANGE: ci-SPLIT staging for occupancy. LDS now holds only HALF the
// channels of the 26x18 halo: 468 px x 32 ci x 2 B = 29952 B -> 4
// blocks/CU (16 waves, 4 waves/SIMD) vs 2 before. Each expert = two
// half-K passes accumulating into the same acc; zigzag half order
// (e11:h0,h1 -> e7:h1,h0 -> e3:h0,h1 -> e1:h1,h0) reuses the resident
// half -> only 5 stage phases total. VGPR budget kept <=128 (the
// compiler's wall, proven by R5's spill): depth-1 pair-loop, A-buf 16 +
// B-buf 32 + acc 32 + mix 32 + addr ~12.
// LDS swizzle: 16B chunk c (0..3) of pixel px stored at slot c ^ (px&3).
// Read (kcl,kh) -> slot (2*kcl+kh) ^ (px&3): all 8 bank-quads get exactly
// 8 lanes per ds_read_b128 (the wave64 minimum) -> conflict-free.
__device__ __forceinline__ v16f mfma32(v8s a, v8s b, v16f c) {
    return __builtin_amdgcn_mfma_f32_32x32x16_bf16(a, b, c, 0, 0, 0);
}

__device__ __forceinline__ void stage_half(const unsigned short* __restrict__ xT,
                                           unsigned short* sx, int b, int x0,
                                           int y0, int h, int tid) {
    for (int i = tid; i < 1872; i += 256) {
        int px = i >> 2, c = i & 3;
        int hrow = px / 18;
        int hcol = px - hrow * 18;
        int gy = y0 + hrow - 5, gx = x0 + hcol - 5;
        v8s v = {0, 0, 0, 0, 0, 0, 0, 0};
        if ((unsigned)gy < 256u && (unsigned)gx < 256u)
            v = *(const v8s*)(xT +
                (((size_t)(b * 256 + gy) * 256 + gx) * 64 + h * 32 + c * 8));
        int cs = c ^ (px & 3);
        *(v8s*)(sx + px * 32 + cs * 8) = v;
    }
}

// A-fragment (half-K): pixel px, kcl 0..1. slot(kcl=0)=kh^(px&3); kcl=1 -> ^2
#define LDA2(A, pxv)                                            \
    {                                                           \
        int _px = (pxv);                                        \
        const char* _ap = sxb + _px * 64;                       \
        int _o = (khh ^ (_px & 3)) << 4;                        \
        A[0] = *(const v8s*)(_ap + _o);                         \
        A[1] = *(const v8s*)(_ap + (_o ^ 32));                  \
    }

// B-fragment (half-K): wp = tap base + lane*16 + h*2048.
// B[0..1] = nt0 kcl 0..1; B[2..3] = nt1 kcl 0..1.
#define LDB4(B, wpv)                                            \
    {                                                           \
        const char* _wp = (wpv);                                \
        B[0] = *(const v8s*)(_wp);                              \
        B[1] = *(const v8s*)(_wp + 1024);                       \
        B[2] = *(const v8s*)(_wp + 4096);                       \
        B[3] = *(const v8s*)(_wp + 5120);                       \
    }

#define MM4(A, B)                                               \
    {                                                           \
        __builtin_amdgcn_s_setprio(1);                          \
        a0 = mfma32(A[0], B[0], a0);                            \
        a1 = mfma32(A[0], B[2], a1);                            \
        a0 = mfma32(A[1], B[1], a0);                            \
        a1 = mfma32(A[1], B[3], a1);                            \
        __builtin_amdgcn_s_setprio(0);                          \
    }

#define ADV()                                                   \
    {                                                           \
        dxc++; px++; wp += 8192;                                \
        if (dxc == KS) { dxc = 0; px += 18 - KS; }              \
    }

template <int KS, int OFF>
__device__ __forceinline__ void pass_half(const char* sxb, const char* wbase,
                                          int p00, int khh, v16f& a0, v16f& a1) {
    const char* wp = wbase;          // tap stride 8192 B
    int px = p00 + OFF * 19;
    int dxc = 0;
    v8s A0[2], A1[2], B0[4], B1[4];
    LDA2(A0, px);
    LDB4(B0, wp);
#pragma unroll 1
    for (int i = 0; i < (KS * KS - 1) / 2; ++i) {
        ADV();
        LDA2(A1, px);
        LDB4(B1, wp);
        MM4(A0, B0);
        ADV();
        LDA2(A0, px);
        LDB4(B0, wp);
        MM4(A1, B1);
    }
    MM4(A0, B0);
}

#define ZACC()                                                  \
    {                                                           \
        _Pragma("unroll")                                       \
        for (int _r = 0; _r < 16; ++_r) { a0[_r] = 0.f; a1[_r] = 0.f; } \
    }

#define FOLD(CIDX, eb)                                          \
    {                                                           \
        float ce = coef[CIDX];                                  \
        float b0v = eb[n];                                      \
        float b1v = eb[32 + n];                                 \
        _Pragma("unroll")                                       \
        for (int _r = 0; _r < 16; ++_r) {                       \
            float z0 = a0[_r] + b0v;                            \
            float z1 = a1[_r] + b1v;                            \
            mix0[_r] = fmaf(ce, 1.f / (1.f + __expf(-z0)), mix0[_r]); \
            mix1[_r] = fmaf(ce, 1.f / (1.f + __expf(-z1)), mix1[_r]); \
        }                                                       \
    }

__global__ __launch_bounds__(256, 4) void moe32_kernel(
        const unsigned short* __restrict__ xT, const unsigned short* __restrict__ wT,
        const float* __restrict__ x,
        const float* __restrict__ eb1, const float* __restrict__ eb3,
        const float* __restrict__ eb7, const float* __restrict__ eb11,
        const float* __restrict__ coef, float* __restrict__ out) {
    __shared__ unsigned short sx[468 * 32];  // 29952 B
    int blk = blockIdx.x;
    int xt = blk & 31, yt = (blk >> 5) & 15, b = blk >> 9;
    int x0 = xt * 8, y0 = yt * 16;
    int tid = threadIdx.x;

    int lane = tid & 63, w = tid >> 6;
    int kh = lane >> 5, n = lane & 31;
    int prow = (lane & 31) >> 3, pcol = lane & 7;
    int p00 = (w * 4 + prow) * 18 + pcol;
    int khh = kh;
    const char* sxb = (const char*)sx;
    const char* wl = (const char*)wT + (lane << 4);
    const char* w1 = wl;                    // e1:  tap 0
    const char* w3 = wl + 1 * 8192;         // e3:  taps 1-9
    const char* w7 = wl + 10 * 8192;        // e7:  taps 10-58
    const char* w11 = wl + 59 * 8192;       // e11: taps 59-179

    v16f mix0, mix1, a0, a1;
#pragma unroll
    for (int r = 0; r < 16; ++r) { mix0[r] = 0.f; mix1[r] = 0.f; }

    // ---- zigzag: 5 stages cover 4 experts x 2 ci-halves ----
    stage_half(xT, sx, b, x0, y0, 0, tid);
    __syncthreads();
    ZACC();
    pass_half<11, 0>(sxb, w11, p00, khh, a0, a1);
    __syncthreads();
    stage_half(xT, sx, b, x0, y0, 1, tid);
    __syncthreads();
    pass_half<11, 0>(sxb, w11 + 2048, p00, khh, a0, a1);
    FOLD(3, eb11);
    ZACC();
    pass_half<7, 2>(sxb, w7 + 2048, p00, khh, a0, a1);
    __syncthreads();
    stage_half(xT, sx, b, x0, y0, 0, tid);
    __syncthreads();
    pass_half<7, 2>(sxb, w7, p00, khh, a0, a1);
    FOLD(2, eb7);
    ZACC();
    pass_half<3, 4>(sxb, w3, p00, khh, a0, a1);
    __syncthreads();
    stage_half(xT, sx, b, x0, y0, 1, tid);
    __syncthreads();
    pass_half<3, 4>(sxb, w3 + 2048, p00, khh, a0, a1);
    FOLD(1, eb3);
    ZACC();
    pass_half<1, 5>(sxb, w1 + 2048, p00, khh, a0, a1);
    __syncthreads();
    stage_half(xT, sx, b, x0, y0, 0, tid);
    __syncthreads();
    pass_half<1, 5>(sxb, w1, p00, khh, a0, a1);
    FOLD(0, eb1);

    // ---- final: out = x * mix ----
    size_t pb0 = ((size_t)(b * 64 + n)) * 65536;
    size_t pb1 = ((size_t)(b * 64 + 32 + n)) * 65536;
    int yb = y0 + w * 4, xb = x0 + kh * 4;
#pragma unroll
    for (int g = 0; g < 4; ++g) {
        size_t off = (size_t)(yb + g) * 256 + xb;
        v4f xv0 = *(const v4f*)(x + pb0 + off);
        v4f xv1 = *(const v4f*)(x + pb1 + off);
        v4f o0, o1;
#pragma unroll
        for (int r = 0; r < 4; ++r) {
            o0[r] = xv0[r] * mix0[g * 4 + r];
            o1[r] = xv1[r] * mix1[g * 4 + r];
        }
        *(v4f*)(out + pb0 + off) = o0;
        *(v4f*)(out + pb1 + off) = o1;
    }
}

// ---------------- fallback direct conv (R1, verified) ------------------
__global__ __launch_bounds__(256) void conv_kernel(const float* __restrict__ x,
                                                   const float* __restrict__ ew1,
                                                   const float* __restrict__ eb1,
                                                   const float* __restrict__ ew3,
                                                   const float* __restrict__ eb3,
                                                   const float* __restrict__ ew7,
                                                   const float* __restrict__ eb7,
                                                   const float* __restrict__ ew11,
                                                   const float* __restrict__ eb11,
                                                   const float* __restrict__ coef,
                                                   float* __restrict__ out) {
    int blk = blockIdx.x;
    int y = blk & (HH - 1);
    int c = (blk >> 8) & (CH - 1);
    int b = blk >> 14;
    int xi = threadIdx.x;
    const size_t plane = (size_t)HH * WW;
    float a0 = 0.f, a1 = 0.f, a2 = 0.f, a3 = 0.f;
    for (int dy = 0; dy < 11; dy++) {
        int yy = y + dy - 5;
        if (yy < 0 || yy >= HH) continue;
        bool in7y = (dy >= 2 && dy <= 8);
        bool in3y = (dy >= 4 && dy <= 6);
        bool in1y = (dy == 5);
        for (int ci = 0; ci < CH; ci++) {
            const float* xrow = x + ((size_t)(b * CH + ci)) * plane + (size_t)yy * WW;
            const float* w11row = ew11 + (((c * CH + ci) * 11 + dy) * 11);
            const float* w7row = in7y ? (ew7 + (((c * CH + ci) * 7 + (dy - 2)) * 7)) : ew7;
            const float* w3row = in3y ? (ew3 + (((c * CH + ci) * 3 + (dy - 4)) * 3)) : ew3;
            float w1v = in1y ? ew1[c * CH + ci] : 0.f;
#pragma unroll
            for (int dx = 0; dx < 11; dx++) {
                int xc = xi + dx - 5;
                float xv = (xc >= 0 && xc < WW) ? xrow[xc] : 0.f;
                a3 = fmaf(w11row[dx], xv, a3);
                if (dx >= 2 && dx <= 8) { if (in7y) a2 = fmaf(w7row[dx - 2], xv, a2); }
                if (dx >= 4 && dx <= 6) { if (in3y) a1 = fmaf(w3row[dx - 4], xv, a1); }
                if (dx == 5) { if (in1y) a0 = fmaf(w1v, xv, a0); }
            }
        }
    }
    a0 += eb1[c]; a1 += eb3[c]; a2 += eb7[c]; a3 += eb11[c];
    float s0 = 1.f / (1.f + expf(-a0));
    float s1 = 1.f / (1.f + expf(-a1));
    float s2 = 1.f / (1.f + expf(-a2));
    float s3 = 1.f / (1.f + expf(-a3));
    float mix = coef[0] * s0 + coef[1] * s1 + coef[2] * s2 + coef[3] * s3;
    size_t idx = ((size_t)(b * CH + c)) * plane + (size_t)y * WW + xi;
    out[idx] = x[idx] * mix;
}

extern "C" void kernel_launch(void* const* d_in, const int* in_sizes, int n_in,
                              void* d_out, int out_size, void* d_ws, size_t ws_size,
                              hipStream_t stream) {
    const float* x = (const float*)d_in[0];
    const float* gw1 = (const float*)d_in[1];
    const float* gb1 = (const float*)d_in[2];
    const float* gw2 = (const float*)d_in[3];
    const float* gb2 = (const float*)d_in[4];
    const float* ew1 = (const float*)d_in[5];
    const float* eb1 = (const float*)d_in[6];
    const float* ew3 = (const float*)d_in[7];
    const float* eb3 = (const float*)d_in[8];
    const float* ew7 = (const float*)d_in[9];
    const float* eb7 = (const float*)d_in[10];
    const float* ew11 = (const float*)d_in[11];
    const float* eb11 = (const float*)d_in[12];

    float* out = (float*)d_out;
    float* wsf = (float*)d_ws;
    float* g = wsf;                                // 512 floats
    float* coef = wsf + 512;                       // 4 floats (+pad to 520)
    unsigned short* wT = (unsigned short*)((char*)d_ws + 2080);       // 737280 bf16
    unsigned short* xT = (unsigned short*)((char*)d_ws + 1476640);    // 33.55M bf16
    float* loss_out = out + (out_size - 1);
    const size_t need = 1476640ull + 67108864ull;

    mean_kernel<<<BATCH * CH, 256, 0, stream>>>(x, g);
    gate_kernel<<<1, 512, 0, stream>>>(g, gw1, gb1, gw2, gb2, coef, loss_out);

    if (ws_size >= need) {
        wtrans_kernel<<<360, 256, 0, stream>>>(ew1, ew3, ew7, ew11, wT);
        xtrans_kernel<<<BATCH * HH, 256, 0, stream>>>(x, xT);
        moe32_kernel<<<4096, 256, 0, stream>>>(xT, wT, x, eb1, eb3, eb7, eb11, coef, out);
    } else {
        conv_kernel<<<BATCH * CH * HH, 256, 0, stream>>>(x, ew1, eb1, ew3, eb3, ew7, eb7,
                                                         ew11, eb11, coef, out);
    }
}